// Round 1
// baseline (63.431 us; speedup 1.0000x reference)
//
#include <hip/hip_runtime.h>

// DendriticLayer: N_IN=1024, N_OUT=256, B=512, T=100 steps, dt=1
// CONN mask = sequential even partition -> output o reads inputs [4o, 4o+4).
// Per (b,o): 4-input PSP sum -> leaky integrator -> soft-argmax over time.

#define N_IN   1024
#define N_OUT  256
#define BATCH  512
#define NSTEPS 100

__global__ __launch_bounds__(N_OUT) void dendritic_kernel(
    const float* __restrict__ spikes,  // [B, N_IN]
    const float* __restrict__ W,       // [N_OUT, N_IN]
    float* __restrict__ out)           // [B, N_OUT]
{
    const int b = blockIdx.x;
    const int o = threadIdx.x;

    // Coalesced float4 loads: spikes[b, 4o..4o+4), W[o, 4o..4o+4)
    const float4 s4 = *reinterpret_cast<const float4*>(spikes + b * N_IN + o * 4);
    const float4 w4 = *reinterpret_cast<const float4*>(W + o * N_IN + o * 4);

    float s[4] = {s4.x, s4.y, s4.z, s4.w};
    float w[4] = {w4.x, w4.y, w4.z, w4.w};

    // Spike activates at first integer t >= s, i.e. t0 = ceil(s),
    // with PSP value w * exp(-(t0 - s)/tau_syn). tau_syn = 5 -> rate 0.2.
    int   t0[4];
    float init[4];
#pragma unroll
    for (int j = 0; j < 4; ++j) {
        float c = ceilf(s[j]);
        t0[j]   = (int)c;
        init[j] = w[j] * __expf((s[j] - c) * 0.2f);
    }

    const float decay = 0.8187307530779818f;  // exp(-dt/tau_syn) = exp(-0.2)

    float p[4] = {0.f, 0.f, 0.f, 0.f};
    float v   = 0.f;
    float den = 0.f;
    float num = 0.f;

#pragma unroll 4
    for (int t = 0; t < NSTEPS; ++t) {
#pragma unroll
        for (int j = 0; j < 4; ++j) {
            p[j] *= decay;
            if (t == t0[j]) p[j] = init[j];  // v_cndmask, no divergence
        }
        float I = (p[0] + p[1]) + (p[2] + p[3]);
        // v += (I - v) * dt/tau_mem, tau_mem = 10
        v = fmaf(I - v, 0.1f, v);
        // softmax over time, temperature tau_soft = 0.5 -> x = 2v.
        // v in [0, ~6] so exp(2v) <= ~7e4: no max-subtraction needed in fp32.
        float e = __expf(v * 2.0f);
        den += e;
        num = fmaf(e, (float)t, num);
    }

    out[b * N_OUT + o] = num / den;
}

extern "C" void kernel_launch(void* const* d_in, const int* in_sizes, int n_in,
                              void* d_out, int out_size, void* d_ws, size_t ws_size,
                              hipStream_t stream) {
    const float* spikes = (const float*)d_in[0];  // [512, 1024]
    const float* W      = (const float*)d_in[1];  // [256, 1024]
    float* out          = (float*)d_out;          // [512, 256]

    dendritic_kernel<<<BATCH, N_OUT, 0, stream>>>(spikes, W, out);
}

// Round 2
// 61.670 us; speedup vs baseline: 1.0285x; 1.0285x over previous
//
#include <hip/hip_runtime.h>
#include <math.h>

// DendriticLayer: N_IN=1024, N_OUT=256, B=512, T=100 steps, dt=1
// CONN = sequential even partition -> output o reads inputs [4o, 4o+4).
//
// Algebra: psp_j(t) = [t >= s_j] * w_j * exp(-(t-s_j)/5)
//                   = [t >= s_j] * A_j * exp(-t/5),   A_j = w_j * exp(s_j/5)
// v_t = 0.9 v_{t-1} + 0.1 * I_t,  I_t = exp(-t/5) * sum_j [t>=s_j] A_j
// Full unroll makes t, (float)t and 0.1*exp(-t/5) compile-time literals:
// per-step body = 4 cmp + 4 cndmask + 3 add + 1 mul + 1 fma + 1 exp + 2 acc.

#define N_IN   1024
#define N_OUT  256
#define BATCH  512
#define NSTEPS 100

__global__ __launch_bounds__(N_OUT) void dendritic_kernel(
    const float* __restrict__ spikes,  // [B, N_IN]
    const float* __restrict__ W,       // [N_OUT, N_IN]
    float* __restrict__ out)           // [B, N_OUT]
{
    const int b = blockIdx.x;
    const int o = threadIdx.x;

    // Coalesced float4 loads: spikes[b, 4o..4o+4), W[o, 4o..4o+4)
    const float4 s4 = *reinterpret_cast<const float4*>(spikes + b * N_IN + o * 4);
    const float4 w4 = *reinterpret_cast<const float4*>(W + o * N_IN + o * 4);

    // Hoisted spike amplitudes. s in [0,100) -> exp(s/5) <= e^20 ~ 4.9e8, fp32-safe.
    const float A0 = w4.x * __expf(0.2f * s4.x);
    const float A1 = w4.y * __expf(0.2f * s4.y);
    const float A2 = w4.z * __expf(0.2f * s4.z);
    const float A3 = w4.w * __expf(0.2f * s4.w);

    float v = 0.f;
    float den0 = 0.f, den1 = 0.f;   // split accumulators: halve the add chains
    float num0 = 0.f, num1 = 0.f;

#pragma unroll
    for (int t = 0; t < NSTEPS; ++t) {
        const float tf = (float)t;                            // literal
        const float E  = 0.1f * __builtin_expf(-0.2f * tf);   // const-folded literal
        float S = (s4.x <= tf ? A0 : 0.f)
                + (s4.y <= tf ? A1 : 0.f)
                + (s4.z <= tf ? A2 : 0.f)
                + (s4.w <= tf ? A3 : 0.f);
        v = fmaf(0.9f, v, E * S);          // v += (I - v)/10
        const float e = __expf(2.0f * v);  // softmax weight, tau_soft=0.5
        if (t & 1) { den1 += e; num1 = fmaf(e, tf, num1); }
        else       { den0 += e; num0 = fmaf(e, tf, num0); }
    }

    out[b * N_OUT + o] = (num0 + num1) / (den0 + den1);
}

extern "C" void kernel_launch(void* const* d_in, const int* in_sizes, int n_in,
                              void* d_out, int out_size, void* d_ws, size_t ws_size,
                              hipStream_t stream) {
    const float* spikes = (const float*)d_in[0];  // [512, 1024]
    const float* W      = (const float*)d_in[1];  // [256, 1024]
    float* out          = (float*)d_out;          // [512, 256]

    dendritic_kernel<<<BATCH, N_OUT, 0, stream>>>(spikes, W, out);
}